// Round 6
// baseline (390.859 us; speedup 1.0000x reference)
//
#include <hip/hip_runtime.h>

using u16 = unsigned short;
using u32 = unsigned int;
typedef __attribute__((ext_vector_type(8))) short short8;  // 8 bf16 (4 VGPRs)
typedef __attribute__((ext_vector_type(4))) float f32x4;   // MFMA 16x16 C/D

#define MFMA16(A, B, C) __builtin_amdgcn_mfma_f32_16x16x32_bf16((A), (B), (C), 0, 0, 0)
#define SCALE 0.125f

// ---------- bf16 helpers ----------
__device__ __forceinline__ u16 f2bf(float f) {
  union { float f; u32 i; } v; v.f = f;
  u32 x = v.i;
  return (u16)((x + 0x7fffu + ((x >> 16) & 1u)) >> 16);  // RNE
}

// ============================================================
// Prep A: ft fp32 -> Xbf bf16 (16384x512)
// ============================================================
__global__ __launch_bounds__(256) void conv_x(const float* __restrict__ X,
                                              u16* __restrict__ Xbf) {
  const int i = (blockIdx.x * 256 + threadIdx.x) * 8;
  float4 a = *(const float4*)(X + i);
  float4 b = *(const float4*)(X + i + 4);
  float v[8] = {a.x, a.y, a.z, a.w, b.x, b.y, b.z, b.w};
  uint4 o;
  o.x = (u32)f2bf(v[0]) | ((u32)f2bf(v[1]) << 16);
  o.y = (u32)f2bf(v[2]) | ((u32)f2bf(v[3]) << 16);
  o.z = (u32)f2bf(v[4]) | ((u32)f2bf(v[5]) << 16);
  o.w = (u32)f2bf(v[6]) | ((u32)f2bf(v[7]) << 16);
  *(uint4*)(Xbf + i) = o;
}

// ============================================================
// Prep B: transpose+convert W[512][N] fp32 -> Wt[N][512] bf16
// z=0: w_qkv (N=1536), z=1: w_out (N=512)
// ============================================================
__global__ __launch_bounds__(256) void transpose_w(
    const float* __restrict__ Wq, const float* __restrict__ Wo,
    u16* __restrict__ Wqt, u16* __restrict__ Wot) {
  const int z = blockIdx.z;
  if (z == 1 && blockIdx.x >= 16) return;
  const float* src = z ? Wo : Wq;
  u16* dst = z ? Wot : Wqt;
  const int ncols = z ? 512 : 1536;
  __shared__ float tile[32][33];
  const int t = threadIdx.x;
  const int kt = blockIdx.y * 32, nt = blockIdx.x * 32;
  const int r = t >> 3, c4 = (t & 7) * 4;
  float4 v = *(const float4*)(src + (size_t)(kt + r) * ncols + nt + c4);
  tile[r][c4 + 0] = v.x; tile[r][c4 + 1] = v.y;
  tile[r][c4 + 2] = v.z; tile[r][c4 + 3] = v.w;
  __syncthreads();
  u16 o0 = f2bf(tile[c4 + 0][r]), o1 = f2bf(tile[c4 + 1][r]);
  u16 o2 = f2bf(tile[c4 + 2][r]), o3 = f2bf(tile[c4 + 3][r]);
  uint2 p = make_uint2((u32)o0 | ((u32)o1 << 16), (u32)o2 | ((u32)o3 << 16));
  *(uint2*)(dst + (size_t)(nt + r) * 512 + kt + c4) = p;
}

// ============================================================
// Kernel 1: QKV GEMM (MFMA). C[16384][1536] = Xbf @ Wt^T + bias,
// scattered to Qp[b][h][n][64], Kp[b][h][n][64], Vt[b][h][64][n] (bf16).
// ============================================================
__global__ __launch_bounds__(256) void qkv_gemm(
    const u16* __restrict__ Xbf, const u16* __restrict__ Wt,
    const float* __restrict__ Bias,
    u16* __restrict__ Qp, u16* __restrict__ Kp, u16* __restrict__ Vt) {
  __shared__ u16 Xs[128][40];
  __shared__ u16 Ws[128][40];
  const int t = threadIdx.x;
  const int bm = blockIdx.y * 128, bn = blockIdx.x * 128;
  const int w = t >> 6, lane = t & 63, quad = lane >> 4, l16 = lane & 15;
  const int mtb = (w >> 1) * 64, ntb = (w & 1) * 64;
  const int lr = t >> 1, lk = (t & 1) * 16;

  f32x4 acc[4][4];
  const f32x4 z4 = {0.f, 0.f, 0.f, 0.f};
  #pragma unroll
  for (int mi = 0; mi < 4; mi++)
    #pragma unroll
    for (int ni = 0; ni < 4; ni++) acc[mi][ni] = z4;

  for (int k0 = 0; k0 < 512; k0 += 32) {
    __syncthreads();
    *(uint4*)&Xs[lr][lk]     = *(const uint4*)(Xbf + (size_t)(bm + lr) * 512 + k0 + lk);
    *(uint4*)&Xs[lr][lk + 8] = *(const uint4*)(Xbf + (size_t)(bm + lr) * 512 + k0 + lk + 8);
    *(uint4*)&Ws[lr][lk]     = *(const uint4*)(Wt + (size_t)(bn + lr) * 512 + k0 + lk);
    *(uint4*)&Ws[lr][lk + 8] = *(const uint4*)(Wt + (size_t)(bn + lr) * 512 + k0 + lk + 8);
    __syncthreads();
    short8 af[4], bf[4];
    #pragma unroll
    for (int mi = 0; mi < 4; mi++)
      af[mi] = *(const short8*)&Xs[mtb + mi * 16 + l16][quad * 8];
    #pragma unroll
    for (int ni = 0; ni < 4; ni++)
      bf[ni] = *(const short8*)&Ws[ntb + ni * 16 + l16][quad * 8];
    #pragma unroll
    for (int mi = 0; mi < 4; mi++)
      #pragma unroll
      for (int ni = 0; ni < 4; ni++)
        acc[mi][ni] = MFMA16(af[mi], bf[ni], acc[mi][ni]);
  }

  #pragma unroll
  for (int ni = 0; ni < 4; ni++) {
    const int g = bn + ntb + ni * 16;
    const int h = g / 192, rr = g % 192;
    const int type = rr >> 6, dbase = rr & 63;
    const float bias = Bias[g + l16];
    #pragma unroll
    for (int mi = 0; mi < 4; mi++) {
      const int row0 = bm + mtb + mi * 16 + quad * 4;
      const int b = row0 >> 10, n0 = row0 & 1023;
      const size_t bh = (size_t)(b * 8 + h) * 65536;
      if (type == 2) {  // V -> Vt[b][h][d][n]
        u16 o[4];
        #pragma unroll
        for (int r = 0; r < 4; r++) o[r] = f2bf(acc[mi][ni][r] + bias);
        uint2 p = make_uint2((u32)o[0] | ((u32)o[1] << 16),
                             (u32)o[2] | ((u32)o[3] << 16));
        *(uint2*)(Vt + bh + (size_t)(dbase + l16) * 1024 + n0) = p;
      } else {
        u16* dst = (type ? Kp : Qp) + bh;
        #pragma unroll
        for (int r = 0; r < 4; r++)
          dst[(size_t)(n0 + r) * 64 + dbase + l16] = f2bf(acc[mi][ni][r] + bias);
      }
    }
  }
}

// ============================================================
// Kernel 2 v2: flash attention (MFMA), per (qt2, h, b), 4 waves,
// 16 queries/wave (reg pressure: ~100 regs -> 4 waves/SIMD).
// Q/K/V frags direct global->reg; LDS only for P round-trip,
// per-wave rows, no barriers.
// ============================================================
__global__ __launch_bounds__(256, 4) void attn_mfma(
    const u16* __restrict__ Qp, const u16* __restrict__ Kp,
    const u16* __restrict__ Vt, u16* __restrict__ ATT) {
  __shared__ u16 Ps[64][136];  // [q][key], 17.4 KB
  const int t = threadIdx.x, w = t >> 6, lane = t & 63;
  const int quad = lane >> 4, l16 = lane & 15;
  const int qt2 = blockIdx.x, h = blockIdx.y, b = blockIdx.z;
  const size_t bh = (size_t)(b * 8 + h) * 65536;
  const u16* Qb = Qp + bh;  // [1024][64]
  const u16* Kb = Kp + bh;  // [1024][64]
  const u16* Vb = Vt + bh;  // [64][1024]
  const int q0 = qt2 * 64 + w * 16;  // wave's first query row

  // Q A-frags: A[m=l16][k=quad*8+j], held whole kernel (8 regs)
  short8 qf[2];
  #pragma unroll
  for (int ks = 0; ks < 2; ks++)
    qf[ks] = *(const short8*)(Qb + (size_t)(q0 + l16) * 64 + ks * 32 + quad * 8);

  float m_[4], l_[4];
  f32x4 Of[4];
  const f32x4 z4 = {0.f, 0.f, 0.f, 0.f};
  #pragma unroll
  for (int r = 0; r < 4; r++) { m_[r] = -1e30f; l_[r] = 0.f; }
  #pragma unroll
  for (int ni = 0; ni < 4; ni++) Of[ni] = z4;

  for (int kt = 0; kt < 8; kt++) {
    // ---- S = Q K^T over 128 keys (16 MFMA) ----
    f32x4 s[8];
    #pragma unroll
    for (int nt = 0; nt < 8; nt++) s[nt] = z4;
    #pragma unroll
    for (int nt = 0; nt < 8; nt++) {
      const u16* kp = Kb + (size_t)(kt * 128 + nt * 16 + l16) * 64 + quad * 8;
      short8 k0f = *(const short8*)(kp);
      short8 k1f = *(const short8*)(kp + 32);
      s[nt] = MFMA16(qf[0], k0f, s[nt]);
      s[nt] = MFMA16(qf[1], k1f, s[nt]);
    }
    // ---- online softmax (row = quad*4+r, cols over 16-lane group) ----
    #pragma unroll
    for (int r = 0; r < 4; r++) {
      float mloc = -1e30f;
      #pragma unroll
      for (int nt = 0; nt < 8; nt++) mloc = fmaxf(mloc, s[nt][r]);
      mloc *= SCALE;
      #pragma unroll
      for (int off = 8; off >= 1; off >>= 1)
        mloc = fmaxf(mloc, __shfl_xor(mloc, off));
      const float mnew = fmaxf(m_[r], mloc);
      const float alpha = __expf(m_[r] - mnew);
      float rs = 0.f;
      #pragma unroll
      for (int nt = 0; nt < 8; nt++) {
        float p = __expf(fmaf(s[nt][r], SCALE, -mnew));
        s[nt][r] = p; rs += p;
      }
      #pragma unroll
      for (int off = 8; off >= 1; off >>= 1) rs += __shfl_xor(rs, off);
      l_[r] = l_[r] * alpha + rs;
      m_[r] = mnew;
      #pragma unroll
      for (int ni = 0; ni < 4; ni++) Of[ni][r] *= alpha;
    }
    // ---- P: C-layout regs -> LDS bf16 (per-wave rows, no barrier) ----
    #pragma unroll
    for (int nt = 0; nt < 8; nt++)
      #pragma unroll
      for (int r = 0; r < 4; r++)
        Ps[w * 16 + quad * 4 + r][nt * 16 + l16] = f2bf(s[nt][r]);
    // ---- O += P V (16 MFMA) ----
    #pragma unroll
    for (int ks = 0; ks < 4; ks++) {
      short8 pa = *(const short8*)&Ps[w * 16 + l16][ks * 32 + quad * 8];
      #pragma unroll
      for (int ni = 0; ni < 4; ni++) {
        short8 vf = *(const short8*)(
            Vb + (size_t)(ni * 16 + l16) * 1024 + kt * 128 + ks * 32 + quad * 8);
        Of[ni] = MFMA16(pa, vf, Of[ni]);
      }
    }
  }
  // ---- epilogue: normalize, ATT[token][h*64+d] bf16 ----
  #pragma unroll
  for (int r = 0; r < 4; r++) {
    const float inv = 1.0f / l_[r];
    const int row = b * 1024 + q0 + quad * 4 + r;
    #pragma unroll
    for (int ni = 0; ni < 4; ni++)
      ATT[(size_t)row * 512 + h * 64 + ni * 16 + l16] = f2bf(Of[ni][r] * inv);
  }
}

// ============================================================
// Kernel 3: OUT = ATT(bf16) @ Wout^T + bias + ft (fp32) -> fp32
// ============================================================
__global__ __launch_bounds__(256) void out_proj(
    const u16* __restrict__ A, const u16* __restrict__ Wt,
    const float* __restrict__ Bias, const float* __restrict__ FT,
    float* __restrict__ OUT) {
  __shared__ u16 As[128][40];
  __shared__ u16 Ws[128][40];
  const int t = threadIdx.x;
  const int bm = blockIdx.y * 128, bn = blockIdx.x * 128;
  const int w = t >> 6, lane = t & 63, quad = lane >> 4, l16 = lane & 15;
  const int mtb = (w >> 1) * 64, ntb = (w & 1) * 64;
  const int lr = t >> 1, lk = (t & 1) * 16;

  f32x4 acc[4][4];
  const f32x4 z4 = {0.f, 0.f, 0.f, 0.f};
  #pragma unroll
  for (int mi = 0; mi < 4; mi++)
    #pragma unroll
    for (int ni = 0; ni < 4; ni++) acc[mi][ni] = z4;

  for (int k0 = 0; k0 < 512; k0 += 32) {
    __syncthreads();
    *(uint4*)&As[lr][lk]     = *(const uint4*)(A + (size_t)(bm + lr) * 512 + k0 + lk);
    *(uint4*)&As[lr][lk + 8] = *(const uint4*)(A + (size_t)(bm + lr) * 512 + k0 + lk + 8);
    *(uint4*)&Ws[lr][lk]     = *(const uint4*)(Wt + (size_t)(bn + lr) * 512 + k0 + lk);
    *(uint4*)&Ws[lr][lk + 8] = *(const uint4*)(Wt + (size_t)(bn + lr) * 512 + k0 + lk + 8);
    __syncthreads();
    short8 af[4], bf[4];
    #pragma unroll
    for (int mi = 0; mi < 4; mi++)
      af[mi] = *(const short8*)&As[mtb + mi * 16 + l16][quad * 8];
    #pragma unroll
    for (int ni = 0; ni < 4; ni++)
      bf[ni] = *(const short8*)&Ws[ntb + ni * 16 + l16][quad * 8];
    #pragma unroll
    for (int mi = 0; mi < 4; mi++)
      #pragma unroll
      for (int ni = 0; ni < 4; ni++)
        acc[mi][ni] = MFMA16(af[mi], bf[ni], acc[mi][ni]);
  }

  #pragma unroll
  for (int ni = 0; ni < 4; ni++) {
    const int g = bn + ntb + ni * 16;
    const float bias = Bias[g + l16];
    #pragma unroll
    for (int mi = 0; mi < 4; mi++) {
      const int row0 = bm + mtb + mi * 16 + quad * 4;
      #pragma unroll
      for (int r = 0; r < 4; r++) {
        const size_t idx = (size_t)(row0 + r) * 512 + g + l16;
        OUT[idx] = acc[mi][ni][r] + bias + FT[idx];
      }
    }
  }
}

// ============================================================
extern "C" void kernel_launch(void* const* d_in, const int* in_sizes, int n_in,
                              void* d_out, int out_size, void* d_ws, size_t ws_size,
                              hipStream_t stream) {
  const float* ft    = (const float*)d_in[0];  // [16][1024][512] f32
  const float* w_qkv = (const float*)d_in[1];  // [512][1536]   f32
  const float* b_qkv = (const float*)d_in[2];  // [1536]        f32
  const float* w_out = (const float*)d_in[3];  // [512][512]    f32
  const float* b_out = (const float*)d_in[4];  // [512]         f32
  float* out = (float*)d_out;                  // [16][1024][512] f32

  char* p = (char*)d_ws;
  u16* Xbf    = (u16*)(p);                              // 16,777,216
  u16* ATT    = Xbf;                                    // alias (Xbf dead)
  u16* Wqkv_t = (u16*)(p + 16777216);                   //  1,572,864
  u16* Wout_t = (u16*)(p + 18350080);                   //    524,288
  u16* Qp     = (u16*)(p + 18874368);                   // 16,777,216
  u16* Kp     = (u16*)(p + 35651584);                   // 16,777,216
  u16* Vt     = (u16*)(p + 52428800);                   // 16,777,216 -> 69.2 MB

  conv_x     <<<4096, 256, 0, stream>>>(ft, Xbf);
  transpose_w<<<dim3(48, 16, 2), 256, 0, stream>>>(w_qkv, w_out, Wqkv_t, Wout_t);
  qkv_gemm   <<<dim3(12, 128), 256, 0, stream>>>(Xbf, Wqkv_t, b_qkv, Qp, Kp, Vt);
  attn_mfma  <<<dim3(16, 8, 16), 256, 0, stream>>>(Qp, Kp, Vt, ATT);
  out_proj   <<<dim3(4, 128), 256, 0, stream>>>(ATT, Wout_t, b_out, ft, out);
}

// Round 7
// 239.976 us; speedup vs baseline: 1.6287x; 1.6287x over previous
//
#include <hip/hip_runtime.h>

using u16 = unsigned short;
using u32 = unsigned int;
typedef __attribute__((ext_vector_type(8))) short short8;  // 8 bf16 (4 VGPRs)
typedef __attribute__((ext_vector_type(4))) float f32x4;   // MFMA 16x16 C/D

#define MFMA16(A, B, C) __builtin_amdgcn_mfma_f32_16x16x32_bf16((A), (B), (C), 0, 0, 0)
#define SCALE 0.125f

// ---------- bf16 helpers ----------
__device__ __forceinline__ u16 f2bf(float f) {
  union { float f; u32 i; } v; v.f = f;
  u32 x = v.i;
  return (u16)((x + 0x7fffu + ((x >> 16) & 1u)) >> 16);  // RNE
}

// ============================================================
// Prep A: ft fp32 -> Xbf bf16 (16384x512)
// ============================================================
__global__ __launch_bounds__(256) void conv_x(const float* __restrict__ X,
                                              u16* __restrict__ Xbf) {
  const int i = (blockIdx.x * 256 + threadIdx.x) * 8;
  float4 a = *(const float4*)(X + i);
  float4 b = *(const float4*)(X + i + 4);
  float v[8] = {a.x, a.y, a.z, a.w, b.x, b.y, b.z, b.w};
  uint4 o;
  o.x = (u32)f2bf(v[0]) | ((u32)f2bf(v[1]) << 16);
  o.y = (u32)f2bf(v[2]) | ((u32)f2bf(v[3]) << 16);
  o.z = (u32)f2bf(v[4]) | ((u32)f2bf(v[5]) << 16);
  o.w = (u32)f2bf(v[6]) | ((u32)f2bf(v[7]) << 16);
  *(uint4*)(Xbf + i) = o;
}

// ============================================================
// Prep B: transpose+convert W[512][N] fp32 -> Wt[N][512] bf16
// ============================================================
__global__ __launch_bounds__(256) void transpose_w(
    const float* __restrict__ Wq, const float* __restrict__ Wo,
    u16* __restrict__ Wqt, u16* __restrict__ Wot) {
  const int z = blockIdx.z;
  if (z == 1 && blockIdx.x >= 16) return;
  const float* src = z ? Wo : Wq;
  u16* dst = z ? Wot : Wqt;
  const int ncols = z ? 512 : 1536;
  __shared__ float tile[32][33];
  const int t = threadIdx.x;
  const int kt = blockIdx.y * 32, nt = blockIdx.x * 32;
  const int r = t >> 3, c4 = (t & 7) * 4;
  float4 v = *(const float4*)(src + (size_t)(kt + r) * ncols + nt + c4);
  tile[r][c4 + 0] = v.x; tile[r][c4 + 1] = v.y;
  tile[r][c4 + 2] = v.z; tile[r][c4 + 3] = v.w;
  __syncthreads();
  u16 o0 = f2bf(tile[c4 + 0][r]), o1 = f2bf(tile[c4 + 1][r]);
  u16 o2 = f2bf(tile[c4 + 2][r]), o3 = f2bf(tile[c4 + 3][r]);
  uint2 p = make_uint2((u32)o0 | ((u32)o1 << 16), (u32)o2 | ((u32)o3 << 16));
  *(uint2*)(dst + (size_t)(nt + r) * 512 + kt + c4) = p;
}

// ============================================================
// Kernel 1: QKV GEMM (MFMA) -> Qp[b][h][n][64], Kp[b][h][n][64],
// Vt[b][h][64][n] (bf16). Unchanged from round 5/6.
// ============================================================
__global__ __launch_bounds__(256) void qkv_gemm(
    const u16* __restrict__ Xbf, const u16* __restrict__ Wt,
    const float* __restrict__ Bias,
    u16* __restrict__ Qp, u16* __restrict__ Kp, u16* __restrict__ Vt) {
  __shared__ u16 Xs[128][40];
  __shared__ u16 Ws[128][40];
  const int t = threadIdx.x;
  const int bm = blockIdx.y * 128, bn = blockIdx.x * 128;
  const int w = t >> 6, lane = t & 63, quad = lane >> 4, l16 = lane & 15;
  const int mtb = (w >> 1) * 64, ntb = (w & 1) * 64;
  const int lr = t >> 1, lk = (t & 1) * 16;

  f32x4 acc[4][4];
  const f32x4 z4 = {0.f, 0.f, 0.f, 0.f};
  #pragma unroll
  for (int mi = 0; mi < 4; mi++)
    #pragma unroll
    for (int ni = 0; ni < 4; ni++) acc[mi][ni] = z4;

  for (int k0 = 0; k0 < 512; k0 += 32) {
    __syncthreads();
    *(uint4*)&Xs[lr][lk]     = *(const uint4*)(Xbf + (size_t)(bm + lr) * 512 + k0 + lk);
    *(uint4*)&Xs[lr][lk + 8] = *(const uint4*)(Xbf + (size_t)(bm + lr) * 512 + k0 + lk + 8);
    *(uint4*)&Ws[lr][lk]     = *(const uint4*)(Wt + (size_t)(bn + lr) * 512 + k0 + lk);
    *(uint4*)&Ws[lr][lk + 8] = *(const uint4*)(Wt + (size_t)(bn + lr) * 512 + k0 + lk + 8);
    __syncthreads();
    short8 af[4], bf[4];
    #pragma unroll
    for (int mi = 0; mi < 4; mi++)
      af[mi] = *(const short8*)&Xs[mtb + mi * 16 + l16][quad * 8];
    #pragma unroll
    for (int ni = 0; ni < 4; ni++)
      bf[ni] = *(const short8*)&Ws[ntb + ni * 16 + l16][quad * 8];
    #pragma unroll
    for (int mi = 0; mi < 4; mi++)
      #pragma unroll
      for (int ni = 0; ni < 4; ni++)
        acc[mi][ni] = MFMA16(af[mi], bf[ni], acc[mi][ni]);
  }

  #pragma unroll
  for (int ni = 0; ni < 4; ni++) {
    const int g = bn + ntb + ni * 16;
    const int h = g / 192, rr = g % 192;
    const int type = rr >> 6, dbase = rr & 63;
    const float bias = Bias[g + l16];
    #pragma unroll
    for (int mi = 0; mi < 4; mi++) {
      const int row0 = bm + mtb + mi * 16 + quad * 4;
      const int b = row0 >> 10, n0 = row0 & 1023;
      const size_t bh = (size_t)(b * 8 + h) * 65536;
      if (type == 2) {  // V -> Vt[b][h][d][n]
        u16 o[4];
        #pragma unroll
        for (int r = 0; r < 4; r++) o[r] = f2bf(acc[mi][ni][r] + bias);
        uint2 p = make_uint2((u32)o[0] | ((u32)o[1] << 16),
                             (u32)o[2] | ((u32)o[3] << 16));
        *(uint2*)(Vt + bh + (size_t)(dbase + l16) * 1024 + n0) = p;
      } else {
        u16* dst = (type ? Kp : Qp) + bh;
        #pragma unroll
        for (int r = 0; r < 4; r++)
          dst[(size_t)(n0 + r) * 64 + dbase + l16] = f2bf(acc[mi][ni][r] + bias);
      }
    }
  }
}

// ============================================================
// Kernel 2 v3: flash attention (MFMA). 512 threads = 8 waves,
// 16 q/wave -> 128 q/block; grid 1024 flat, XCD-affinity swizzle
// (all 8 q-blocks of one (b,h) share bx%8 -> same L2).
// K/V tiles LDS-staged once per block with register-prefetch
// double buffering; P round-trip in per-wave LDS rows (no barrier).
// ============================================================
__global__ __launch_bounds__(512, 4) void attn_mfma(
    const u16* __restrict__ Qp, const u16* __restrict__ Kp,
    const u16* __restrict__ Vt, u16* __restrict__ ATT) {
  __shared__ u16 Ks[128][72];   // [key][d]   18.4 KB, row 144 B
  __shared__ u16 Vs[64][136];   // [d][key]   17.4 KB, row 272 B
  __shared__ u16 Ps[128][136];  // [q][key]   34.8 KB, row 272 B
  const int t = threadIdx.x, w = t >> 6, lane = t & 63;
  const int quad = lane >> 4, l16 = lane & 15;
  // XCD-affinity decode: bx%8 fixed per (b,h)
  const int bx = blockIdx.x;
  const int c = bx & 7, g = bx >> 3;
  const int qt = g & 7, u = g >> 3;
  const int bh_id = u * 8 + c;
  const int b = bh_id >> 3, h = bh_id & 7;
  const size_t bh = (size_t)bh_id * 65536;
  const u16* Qb = Qp + bh;  // [1024][64]
  const u16* Kb = Kp + bh;  // [1024][64]
  const u16* Vb = Vt + bh;  // [64][1024]
  const int q0 = qt * 128 + w * 16;  // wave's first query row

  // staging indices (512 threads cover 16 KB K-tile + 16 KB V-tile)
  const int kkey = t >> 2, koff = (t & 3) * 16;  // K: [key][64], 2x uint4
  const int vrow = t >> 3, voff = (t & 7) * 16;  // V: [d][128],  2x uint4
  const u16* Kg = Kb + (size_t)kkey * 64 + koff;
  const u16* Vg = Vb + (size_t)vrow * 1024 + voff;

  // Q A-frags: A[m=l16][k=quad*8+j], held whole kernel
  short8 qf[2];
  #pragma unroll
  for (int ks = 0; ks < 2; ks++)
    qf[ks] = *(const short8*)(Qb + (size_t)(q0 + l16) * 64 + ks * 32 + quad * 8);

  float m_[4], l_[4];
  f32x4 Of[4];
  const f32x4 z4 = {0.f, 0.f, 0.f, 0.f};
  #pragma unroll
  for (int r = 0; r < 4; r++) { m_[r] = -1e30f; l_[r] = 0.f; }
  #pragma unroll
  for (int ni = 0; ni < 4; ni++) Of[ni] = z4;

  // prefetch kt=0 tile into regs
  uint4 kr0 = *(const uint4*)(Kg);
  uint4 kr1 = *(const uint4*)(Kg + 8);
  uint4 vr0 = *(const uint4*)(Vg);
  uint4 vr1 = *(const uint4*)(Vg + 8);

  for (int kt = 0; kt < 8; kt++) {
    __syncthreads();  // prior iter's Ks/Vs reads done
    *(uint4*)&Ks[kkey][koff]     = kr0;
    *(uint4*)&Ks[kkey][koff + 8] = kr1;
    *(uint4*)&Vs[vrow][voff]     = vr0;
    *(uint4*)&Vs[vrow][voff + 8] = vr1;
    if (kt < 7) {  // prefetch next tile; completes during compute
      kr0 = *(const uint4*)(Kg + (kt + 1) * 8192);
      kr1 = *(const uint4*)(Kg + (kt + 1) * 8192 + 8);
      vr0 = *(const uint4*)(Vg + (kt + 1) * 128);
      vr1 = *(const uint4*)(Vg + (kt + 1) * 128 + 8);
    }
    __syncthreads();  // staging visible

    // ---- S = Q K^T over 128 keys (16 MFMA) ----
    f32x4 s[8];
    #pragma unroll
    for (int nt = 0; nt < 8; nt++) s[nt] = z4;
    #pragma unroll
    for (int nt = 0; nt < 8; nt++) {
      short8 k0f = *(const short8*)&Ks[nt * 16 + l16][quad * 8];
      short8 k1f = *(const short8*)&Ks[nt * 16 + l16][quad * 8 + 32];
      s[nt] = MFMA16(qf[0], k0f, s[nt]);
      s[nt] = MFMA16(qf[1], k1f, s[nt]);
    }
    // ---- online softmax (row = quad*4+r, cols over 16-lane group) ----
    #pragma unroll
    for (int r = 0; r < 4; r++) {
      float mloc = -1e30f;
      #pragma unroll
      for (int nt = 0; nt < 8; nt++) mloc = fmaxf(mloc, s[nt][r]);
      mloc *= SCALE;
      #pragma unroll
      for (int off = 8; off >= 1; off >>= 1)
        mloc = fmaxf(mloc, __shfl_xor(mloc, off));
      const float mnew = fmaxf(m_[r], mloc);
      const float alpha = __expf(m_[r] - mnew);
      float rs = 0.f;
      #pragma unroll
      for (int nt = 0; nt < 8; nt++) {
        float p = __expf(fmaf(s[nt][r], SCALE, -mnew));
        s[nt][r] = p; rs += p;
      }
      #pragma unroll
      for (int off = 8; off >= 1; off >>= 1) rs += __shfl_xor(rs, off);
      l_[r] = l_[r] * alpha + rs;
      m_[r] = mnew;
      #pragma unroll
      for (int ni = 0; ni < 4; ni++) Of[ni][r] *= alpha;
    }
    // ---- P: C-layout regs -> LDS bf16 (per-wave rows, no barrier) ----
    #pragma unroll
    for (int nt = 0; nt < 8; nt++)
      #pragma unroll
      for (int r = 0; r < 4; r++)
        Ps[w * 16 + quad * 4 + r][nt * 16 + l16] = f2bf(s[nt][r]);
    // ---- O += P V (16 MFMA) ----
    #pragma unroll
    for (int ks = 0; ks < 4; ks++) {
      short8 pa = *(const short8*)&Ps[w * 16 + l16][ks * 32 + quad * 8];
      #pragma unroll
      for (int ni = 0; ni < 4; ni++) {
        short8 vf = *(const short8*)&Vs[ni * 16 + l16][ks * 32 + quad * 8];
        Of[ni] = MFMA16(pa, vf, Of[ni]);
      }
    }
  }
  // ---- epilogue: normalize, ATT[token][h*64+d] bf16 ----
  #pragma unroll
  for (int r = 0; r < 4; r++) {
    const float inv = 1.0f / l_[r];
    const int row = b * 1024 + q0 + quad * 4 + r;
    #pragma unroll
    for (int ni = 0; ni < 4; ni++)
      ATT[(size_t)row * 512 + h * 64 + ni * 16 + l16] = f2bf(Of[ni][r] * inv);
  }
}

// ============================================================
// Kernel 3: OUT = ATT(bf16) @ Wout^T + bias + ft (fp32) -> fp32
// ============================================================
__global__ __launch_bounds__(256) void out_proj(
    const u16* __restrict__ A, const u16* __restrict__ Wt,
    const float* __restrict__ Bias, const float* __restrict__ FT,
    float* __restrict__ OUT) {
  __shared__ u16 As[128][40];
  __shared__ u16 Ws[128][40];
  const int t = threadIdx.x;
  const int bm = blockIdx.y * 128, bn = blockIdx.x * 128;
  const int w = t >> 6, lane = t & 63, quad = lane >> 4, l16 = lane & 15;
  const int mtb = (w >> 1) * 64, ntb = (w & 1) * 64;
  const int lr = t >> 1, lk = (t & 1) * 16;

  f32x4 acc[4][4];
  const f32x4 z4 = {0.f, 0.f, 0.f, 0.f};
  #pragma unroll
  for (int mi = 0; mi < 4; mi++)
    #pragma unroll
    for (int ni = 0; ni < 4; ni++) acc[mi][ni] = z4;

  for (int k0 = 0; k0 < 512; k0 += 32) {
    __syncthreads();
    *(uint4*)&As[lr][lk]     = *(const uint4*)(A + (size_t)(bm + lr) * 512 + k0 + lk);
    *(uint4*)&As[lr][lk + 8] = *(const uint4*)(A + (size_t)(bm + lr) * 512 + k0 + lk + 8);
    *(uint4*)&Ws[lr][lk]     = *(const uint4*)(Wt + (size_t)(bn + lr) * 512 + k0 + lk);
    *(uint4*)&Ws[lr][lk + 8] = *(const uint4*)(Wt + (size_t)(bn + lr) * 512 + k0 + lk + 8);
    __syncthreads();
    short8 af[4], bf[4];
    #pragma unroll
    for (int mi = 0; mi < 4; mi++)
      af[mi] = *(const short8*)&As[mtb + mi * 16 + l16][quad * 8];
    #pragma unroll
    for (int ni = 0; ni < 4; ni++)
      bf[ni] = *(const short8*)&Ws[ntb + ni * 16 + l16][quad * 8];
    #pragma unroll
    for (int mi = 0; mi < 4; mi++)
      #pragma unroll
      for (int ni = 0; ni < 4; ni++)
        acc[mi][ni] = MFMA16(af[mi], bf[ni], acc[mi][ni]);
  }

  #pragma unroll
  for (int ni = 0; ni < 4; ni++) {
    const int g = bn + ntb + ni * 16;
    const float bias = Bias[g + l16];
    #pragma unroll
    for (int mi = 0; mi < 4; mi++) {
      const int row0 = bm + mtb + mi * 16 + quad * 4;
      #pragma unroll
      for (int r = 0; r < 4; r++) {
        const size_t idx = (size_t)(row0 + r) * 512 + g + l16;
        OUT[idx] = acc[mi][ni][r] + bias + FT[idx];
      }
    }
  }
}

// ============================================================
extern "C" void kernel_launch(void* const* d_in, const int* in_sizes, int n_in,
                              void* d_out, int out_size, void* d_ws, size_t ws_size,
                              hipStream_t stream) {
  const float* ft    = (const float*)d_in[0];  // [16][1024][512] f32
  const float* w_qkv = (const float*)d_in[1];  // [512][1536]   f32
  const float* b_qkv = (const float*)d_in[2];  // [1536]        f32
  const float* w_out = (const float*)d_in[3];  // [512][512]    f32
  const float* b_out = (const float*)d_in[4];  // [512]         f32
  float* out = (float*)d_out;                  // [16][1024][512] f32

  char* p = (char*)d_ws;
  u16* Xbf    = (u16*)(p);                              // 16,777,216
  u16* ATT    = Xbf;                                    // alias (Xbf dead)
  u16* Wqkv_t = (u16*)(p + 16777216);                   //  1,572,864
  u16* Wout_t = (u16*)(p + 18350080);                   //    524,288
  u16* Qp     = (u16*)(p + 18874368);                   // 16,777,216
  u16* Kp     = (u16*)(p + 35651584);                   // 16,777,216
  u16* Vt     = (u16*)(p + 52428800);                   // 16,777,216 -> 69.2 MB

  conv_x     <<<4096, 256, 0, stream>>>(ft, Xbf);
  transpose_w<<<dim3(48, 16, 2), 256, 0, stream>>>(w_qkv, w_out, Wqkv_t, Wout_t);
  qkv_gemm   <<<dim3(12, 128), 256, 0, stream>>>(Xbf, Wqkv_t, b_qkv, Qp, Kp, Vt);
  attn_mfma  <<<dim3(1024), 512, 0, stream>>>(Qp, Kp, Vt, ATT);
  out_proj   <<<dim3(4, 128), 256, 0, stream>>>(ATT, Wout_t, b_out, ft, out);
}

// Round 8
// 219.207 us; speedup vs baseline: 1.7831x; 1.0947x over previous
//
#include <hip/hip_runtime.h>
#include <hip/hip_bf16.h>

using u16 = unsigned short;
using u32 = unsigned int;
typedef __attribute__((ext_vector_type(8))) short short8;  // 8 bf16 (4 VGPRs)
typedef __attribute__((ext_vector_type(4))) float f32x4;   // MFMA 16x16 C/D

#define MFMA16(A, B, C) __builtin_amdgcn_mfma_f32_16x16x32_bf16((A), (B), (C), 0, 0, 0)

// ---------- bf16 helpers ----------
__device__ __forceinline__ u16 f2bf(float f) {
  union { float f; u32 i; } v; v.f = f;
  u32 x = v.i;
  return (u16)((x + 0x7fffu + ((x >> 16) & 1u)) >> 16);  // RNE
}
__device__ __forceinline__ u32 pkbf(float a, float b) {
  union { __hip_bfloat162 h; u32 u; } v;
  v.h = __float22bfloat162_rn(make_float2(a, b));
  return v.u;
}
// async global->LDS, 16B/lane; LDS dest = wave-uniform base + lane*16
__device__ __forceinline__ void gl16(const u16* g, u16* l) {
  __builtin_amdgcn_global_load_lds(
      (const __attribute__((address_space(1))) u32*)g,
      (__attribute__((address_space(3))) u32*)l, 16, 0, 0);
}

// ============================================================
// Prep A: ft fp32 -> Xbf bf16 (16384x512)
// ============================================================
__global__ __launch_bounds__(256) void conv_x(const float* __restrict__ X,
                                              u16* __restrict__ Xbf) {
  const int i = (blockIdx.x * 256 + threadIdx.x) * 8;
  float4 a = *(const float4*)(X + i);
  float4 b = *(const float4*)(X + i + 4);
  uint4 o;
  o.x = pkbf(a.x, a.y); o.y = pkbf(a.z, a.w);
  o.z = pkbf(b.x, b.y); o.w = pkbf(b.z, b.w);
  *(uint4*)(Xbf + i) = o;
}

// ============================================================
// Prep B: transpose+convert W[512][N] fp32 -> Wt[N][512] bf16
// ============================================================
__global__ __launch_bounds__(256) void transpose_w(
    const float* __restrict__ Wq, const float* __restrict__ Wo,
    u16* __restrict__ Wqt, u16* __restrict__ Wot) {
  const int z = blockIdx.z;
  if (z == 1 && blockIdx.x >= 16) return;
  const float* src = z ? Wo : Wq;
  u16* dst = z ? Wot : Wqt;
  const int ncols = z ? 512 : 1536;
  __shared__ float tile[32][33];
  const int t = threadIdx.x;
  const int kt = blockIdx.y * 32, nt = blockIdx.x * 32;
  const int r = t >> 3, c4 = (t & 7) * 4;
  float4 v = *(const float4*)(src + (size_t)(kt + r) * ncols + nt + c4);
  tile[r][c4 + 0] = v.x; tile[r][c4 + 1] = v.y;
  tile[r][c4 + 2] = v.z; tile[r][c4 + 3] = v.w;
  __syncthreads();
  uint2 p = make_uint2(pkbf(tile[c4 + 0][r], tile[c4 + 1][r]),
                       pkbf(tile[c4 + 2][r], tile[c4 + 3][r]));
  *(uint2*)(dst + (size_t)(nt + r) * 512 + kt + c4) = p;
}

// ============================================================
// Kernel 1: QKV GEMM, m97-style: global_load_lds(16B) staging into
// UNPADDED LDS with global-pointer XOR swizzle (chunk ^= (row>>1)&3)
// so frag ds_read_b128 is 2-way (free). Q pre-scaled by 0.125 (exact).
// -> Qp[b][h][n][64]*SCALE, Kp[b][h][n][64], Vt[b][h][64][n] (bf16)
// ============================================================
__global__ __launch_bounds__(256) void qkv_gemm(
    const u16* __restrict__ Xbf, const u16* __restrict__ Wt,
    const float* __restrict__ Bias,
    u16* __restrict__ Qp, u16* __restrict__ Kp, u16* __restrict__ Vt) {
  __shared__ u16 Xs[128][32];  // [m][k] unpadded, 64 B rows
  __shared__ u16 Ws[128][32];  // [n][k]
  const int t = threadIdx.x;
  const int bm = blockIdx.y * 128, bn = blockIdx.x * 128;
  const int w = t >> 6, lane = t & 63, quad = lane >> 4, l16 = lane & 15;
  const int mtb = (w >> 1) * 64, ntb = (w & 1) * 64;
  const int rr = lane >> 2;                                  // row in 16-row group
  const int gch = ((lane & 3) ^ ((lane >> 3) & 3)) * 8;      // swizzled global chunk
  const int sw = (quad ^ ((l16 >> 1) & 3)) * 8;              // frag-read chunk

  const u16* xg0 = Xbf + (size_t)(bm + w * 16 + rr) * 512 + gch;
  const u16* xg1 = xg0 + (size_t)64 * 512;
  const u16* wg0 = Wt + (size_t)(bn + w * 16 + rr) * 512 + gch;
  const u16* wg1 = wg0 + (size_t)64 * 512;
  u16* xl0 = &Xs[w * 16][0]; u16* xl1 = &Xs[64 + w * 16][0];
  u16* wl0 = &Ws[w * 16][0]; u16* wl1 = &Ws[64 + w * 16][0];

  f32x4 acc[4][4];
  const f32x4 z4 = {0.f, 0.f, 0.f, 0.f};
  #pragma unroll
  for (int mi = 0; mi < 4; mi++)
    #pragma unroll
    for (int ni = 0; ni < 4; ni++) acc[mi][ni] = z4;

  for (int k0 = 0; k0 < 512; k0 += 32) {
    gl16(xg0 + k0, xl0);
    gl16(xg1 + k0, xl1);
    gl16(wg0 + k0, wl0);
    gl16(wg1 + k0, wl1);
    __syncthreads();  // drain DMA (vmcnt0) + visibility
    short8 af[4], bf4[4];
    #pragma unroll
    for (int mi = 0; mi < 4; mi++)
      af[mi] = *(const short8*)&Xs[mtb + mi * 16 + l16][sw];
    #pragma unroll
    for (int ni = 0; ni < 4; ni++)
      bf4[ni] = *(const short8*)&Ws[ntb + ni * 16 + l16][sw];
    #pragma unroll
    for (int mi = 0; mi < 4; mi++)
      #pragma unroll
      for (int ni = 0; ni < 4; ni++)
        acc[mi][ni] = MFMA16(af[mi], bf4[ni], acc[mi][ni]);
    __syncthreads();  // reads done before next DMA overwrites
  }

  // epilogue: C-layout (row=quad*4+r, col=l16) -> packed Q/K/V
  #pragma unroll
  for (int ni = 0; ni < 4; ni++) {
    const int g = bn + ntb + ni * 16;
    const int h = g / 192, rm = g % 192;
    const int type = rm >> 6, dbase = rm & 63;
    const float bias = Bias[g + l16];
    const float qsc = (type == 0) ? 0.125f : 1.0f;  // fold softmax scale into Q
    #pragma unroll
    for (int mi = 0; mi < 4; mi++) {
      const int row0 = bm + mtb + mi * 16 + quad * 4;
      const int b = row0 >> 10, n0 = row0 & 1023;
      const size_t bh = (size_t)(b * 8 + h) * 65536;
      if (type == 2) {  // V -> Vt[b][h][d][n]
        uint2 p = make_uint2(pkbf(acc[mi][ni][0] + bias, acc[mi][ni][1] + bias),
                             pkbf(acc[mi][ni][2] + bias, acc[mi][ni][3] + bias));
        *(uint2*)(Vt + bh + (size_t)(dbase + l16) * 1024 + n0) = p;
      } else {
        u16* dst = (type ? Kp : Qp) + bh;
        #pragma unroll
        for (int r = 0; r < 4; r++)
          dst[(size_t)(n0 + r) * 64 + dbase + l16] =
              f2bf((acc[mi][ni][r] + bias) * qsc);
      }
    }
  }
}

// ============================================================
// Kernel 2 v4: flash attention, S^T formulation.
// S^T = MFMA(K-frag, Q-frag): lane holds 4 CONSECUTIVE KEYS of ONE
// query (q=l16) -> softmax reduce = shfl_xor(16,32); P packs to
// uint2 -> 8 ds_write_b64/kt (was 32 scalar). alpha/l via 4 shfl.
// K/V LDS-staged with reg prefetch; XCD-affinity swizzle.
// Q arrives pre-scaled by 0.125 from qkv_gemm.
// ============================================================
__global__ __launch_bounds__(512, 4) void attn_mfma(
    const u16* __restrict__ Qp, const u16* __restrict__ Kp,
    const u16* __restrict__ Vt, u16* __restrict__ ATT) {
  __shared__ u16 Ks[128][72];   // [key][d]
  __shared__ u16 Vs[64][136];   // [d][key]
  __shared__ u16 Ps[128][136];  // [q][key]
  const int t = threadIdx.x, w = t >> 6, lane = t & 63;
  const int quad = lane >> 4, l16 = lane & 15;
  const int bx = blockIdx.x;
  const int c = bx & 7, g = bx >> 3;
  const int qt = g & 7, u = g >> 3;
  const int bh_id = u * 8 + c;
  const int b = bh_id >> 3, h = bh_id & 7;
  const size_t bh = (size_t)bh_id * 65536;
  const u16* Qb = Qp + bh;
  const u16* Kb = Kp + bh;
  const u16* Vb = Vt + bh;
  const int q0 = qt * 128 + w * 16;

  const int kkey = t >> 2, koff = (t & 3) * 16;
  const int vrow = t >> 3, voff = (t & 7) * 16;
  const u16* Kg = Kb + (size_t)kkey * 64 + koff;
  const u16* Vg = Vb + (size_t)vrow * 1024 + voff;

  // Q frags (B-operand for S^T; same per-lane layout as A): 8 regs
  short8 qf[2];
  #pragma unroll
  for (int ks = 0; ks < 2; ks++)
    qf[ks] = *(const short8*)(Qb + (size_t)(q0 + l16) * 64 + ks * 32 + quad * 8);

  float m_ = -1e30f, l_ = 0.f;
  f32x4 Of[4];
  const f32x4 z4 = {0.f, 0.f, 0.f, 0.f};
  #pragma unroll
  for (int ni = 0; ni < 4; ni++) Of[ni] = z4;

  uint4 kr0 = *(const uint4*)(Kg);
  uint4 kr1 = *(const uint4*)(Kg + 8);
  uint4 vr0 = *(const uint4*)(Vg);
  uint4 vr1 = *(const uint4*)(Vg + 8);

  for (int kt = 0; kt < 8; kt++) {
    __syncthreads();
    *(uint4*)&Ks[kkey][koff]     = kr0;
    *(uint4*)&Ks[kkey][koff + 8] = kr1;
    *(uint4*)&Vs[vrow][voff]     = vr0;
    *(uint4*)&Vs[vrow][voff + 8] = vr1;
    if (kt < 7) {
      kr0 = *(const uint4*)(Kg + (kt + 1) * 8192);
      kr1 = *(const uint4*)(Kg + (kt + 1) * 8192 + 8);
      vr0 = *(const uint4*)(Vg + (kt + 1) * 128);
      vr1 = *(const uint4*)(Vg + (kt + 1) * 128 + 8);
    }
    __syncthreads();

    // ---- S^T tiles: D[m=key][n=q] (16 MFMA) ----
    f32x4 s[8];
    #pragma unroll
    for (int nt = 0; nt < 8; nt++) s[nt] = z4;
    #pragma unroll
    for (int nt = 0; nt < 8; nt++) {
      short8 k0f = *(const short8*)&Ks[nt * 16 + l16][quad * 8];
      short8 k1f = *(const short8*)&Ks[nt * 16 + l16][quad * 8 + 32];
      s[nt] = MFMA16(k0f, qf[0], s[nt]);
      s[nt] = MFMA16(k1f, qf[1], s[nt]);
    }
    // ---- softmax: lane owns query q0+l16, keys {16nt + 4quad + r} ----
    float mloc = -1e30f;
    #pragma unroll
    for (int nt = 0; nt < 8; nt++)
      #pragma unroll
      for (int r = 0; r < 4; r++) mloc = fmaxf(mloc, s[nt][r]);
    mloc = fmaxf(mloc, __shfl_xor(mloc, 16));
    mloc = fmaxf(mloc, __shfl_xor(mloc, 32));
    const float mnew = fmaxf(m_, mloc);
    const float alpha = __expf(m_ - mnew);
    float rs = 0.f;
    #pragma unroll
    for (int nt = 0; nt < 8; nt++) {
      float p0 = __expf(s[nt][0] - mnew), p1 = __expf(s[nt][1] - mnew);
      float p2 = __expf(s[nt][2] - mnew), p3 = __expf(s[nt][3] - mnew);
      rs += (p0 + p1) + (p2 + p3);
      *(uint2*)&Ps[w * 16 + l16][nt * 16 + quad * 4] =
          make_uint2(pkbf(p0, p1), pkbf(p2, p3));
    }
    rs += __shfl_xor(rs, 16);
    rs += __shfl_xor(rs, 32);
    l_ = l_ * alpha + rs;
    m_ = mnew;
    // rescale O (rows=queries quad*4+r): fetch alphas from lanes 0..15
    float av[4];
    #pragma unroll
    for (int r = 0; r < 4; r++) av[r] = __shfl(alpha, quad * 4 + r);
    #pragma unroll
    for (int ni = 0; ni < 4; ni++)
      #pragma unroll
      for (int r = 0; r < 4; r++) Of[ni][r] *= av[r];
    // ---- O += P V (16 MFMA) ----
    #pragma unroll
    for (int ks = 0; ks < 4; ks++) {
      short8 pa = *(const short8*)&Ps[w * 16 + l16][ks * 32 + quad * 8];
      #pragma unroll
      for (int ni = 0; ni < 4; ni++) {
        short8 vf = *(const short8*)&Vs[ni * 16 + l16][ks * 32 + quad * 8];
        Of[ni] = MFMA16(pa, vf, Of[ni]);
      }
    }
  }
  // ---- epilogue ----
  float lv[4];
  #pragma unroll
  for (int r = 0; r < 4; r++) lv[r] = __shfl(l_, quad * 4 + r);
  #pragma unroll
  for (int r = 0; r < 4; r++) {
    const float inv = 1.0f / lv[r];
    const int row = b * 1024 + q0 + quad * 4 + r;
    #pragma unroll
    for (int ni = 0; ni < 4; ni++)
      ATT[(size_t)row * 512 + h * 64 + ni * 16 + l16] = f2bf(Of[ni][r] * inv);
  }
}

// ============================================================
// Kernel 3: OUT = ATT(bf16) @ Wout^T + bias + ft(f32) -> f32
// Same m97-style staging as qkv_gemm.
// ============================================================
__global__ __launch_bounds__(256) void out_proj(
    const u16* __restrict__ A, const u16* __restrict__ Wt,
    const float* __restrict__ Bias, const float* __restrict__ FT,
    float* __restrict__ OUT) {
  __shared__ u16 As[128][32];
  __shared__ u16 Ws[128][32];
  const int t = threadIdx.x;
  const int bm = blockIdx.y * 128, bn = blockIdx.x * 128;
  const int w = t >> 6, lane = t & 63, quad = lane >> 4, l16 = lane & 15;
  const int mtb = (w >> 1) * 64, ntb = (w & 1) * 64;
  const int rr = lane >> 2;
  const int gch = ((lane & 3) ^ ((lane >> 3) & 3)) * 8;
  const int sw = (quad ^ ((l16 >> 1) & 3)) * 8;

  const u16* ag0 = A + (size_t)(bm + w * 16 + rr) * 512 + gch;
  const u16* ag1 = ag0 + (size_t)64 * 512;
  const u16* wg0 = Wt + (size_t)(bn + w * 16 + rr) * 512 + gch;
  const u16* wg1 = wg0 + (size_t)64 * 512;
  u16* al0 = &As[w * 16][0]; u16* al1 = &As[64 + w * 16][0];
  u16* wl0 = &Ws[w * 16][0]; u16* wl1 = &Ws[64 + w * 16][0];

  f32x4 acc[4][4];
  const f32x4 z4 = {0.f, 0.f, 0.f, 0.f};
  #pragma unroll
  for (int mi = 0; mi < 4; mi++)
    #pragma unroll
    for (int ni = 0; ni < 4; ni++) acc[mi][ni] = z4;

  for (int k0 = 0; k0 < 512; k0 += 32) {
    gl16(ag0 + k0, al0);
    gl16(ag1 + k0, al1);
    gl16(wg0 + k0, wl0);
    gl16(wg1 + k0, wl1);
    __syncthreads();
    short8 af[4], bf4[4];
    #pragma unroll
    for (int mi = 0; mi < 4; mi++)
      af[mi] = *(const short8*)&As[mtb + mi * 16 + l16][sw];
    #pragma unroll
    for (int ni = 0; ni < 4; ni++)
      bf4[ni] = *(const short8*)&Ws[ntb + ni * 16 + l16][sw];
    #pragma unroll
    for (int mi = 0; mi < 4; mi++)
      #pragma unroll
      for (int ni = 0; ni < 4; ni++)
        acc[mi][ni] = MFMA16(af[mi], bf4[ni], acc[mi][ni]);
    __syncthreads();
  }

  #pragma unroll
  for (int ni = 0; ni < 4; ni++) {
    const int g = bn + ntb + ni * 16;
    const float bias = Bias[g + l16];
    #pragma unroll
    for (int mi = 0; mi < 4; mi++) {
      const int row0 = bm + mtb + mi * 16 + quad * 4;
      #pragma unroll
      for (int r = 0; r < 4; r++) {
        const size_t idx = (size_t)(row0 + r) * 512 + g + l16;
        OUT[idx] = acc[mi][ni][r] + bias + FT[idx];
      }
    }
  }
}

// ============================================================
extern "C" void kernel_launch(void* const* d_in, const int* in_sizes, int n_in,
                              void* d_out, int out_size, void* d_ws, size_t ws_size,
                              hipStream_t stream) {
  const float* ft    = (const float*)d_in[0];  // [16][1024][512] f32
  const float* w_qkv = (const float*)d_in[1];  // [512][1536]   f32
  const float* b_qkv = (const float*)d_in[2];  // [1536]        f32
  const float* w_out = (const float*)d_in[3];  // [512][512]    f32
  const float* b_out = (const float*)d_in[4];  // [512]         f32
  float* out = (float*)d_out;                  // [16][1024][512] f32

  char* p = (char*)d_ws;
  u16* Xbf    = (u16*)(p);                              // 16,777,216
  u16* ATT    = Xbf;                                    // alias (Xbf dead)
  u16* Wqkv_t = (u16*)(p + 16777216);                   //  1,572,864
  u16* Wout_t = (u16*)(p + 18350080);                   //    524,288
  u16* Qp     = (u16*)(p + 18874368);                   // 16,777,216 (pre-scaled)
  u16* Kp     = (u16*)(p + 35651584);                   // 16,777,216
  u16* Vt     = (u16*)(p + 52428800);                   // 16,777,216 -> 69.2 MB

  conv_x     <<<4096, 256, 0, stream>>>(ft, Xbf);
  transpose_w<<<dim3(48, 16, 2), 256, 0, stream>>>(w_qkv, w_out, Wqkv_t, Wout_t);
  qkv_gemm   <<<dim3(12, 128), 256, 0, stream>>>(Xbf, Wqkv_t, b_qkv, Qp, Kp, Vt);
  attn_mfma  <<<dim3(1024), 512, 0, stream>>>(Qp, Kp, Vt, ATT);
  out_proj   <<<dim3(4, 128), 256, 0, stream>>>(ATT, Wout_t, b_out, ft, out);
}